// Round 3
// baseline (1217.231 us; speedup 1.0000x reference)
//
#include <hip/hip_runtime.h>
#include <hip/hip_bf16.h>
#include <stdint.h>

// B=16,T=512,H=1024 -> N=M=8192 rows, H=1024.
// out[0] = mean_i [ log(sum_j exp(sim_ij/T)) - max_j sim_ij / T ]
// out[1] = 1 - mean_i dot(Tn[pos[i]], Tn[pos[i+1]])
// sim computed in fp8 e4m3 via MX-scaled MFMA 16x16x128_f8f6f4 with unity
// scales (e8m0 0x7f = 2^0) -> numerically identical to plain fp8, 2.27x rate.
//
// fp8 tiled layout (per 16-row group of 16KB), K=128 fragment
// (lane l: row l&15, k=(l>>4)*32 + 0..31):
//   row r, k -> group g=r>>4, off = (k>>7)*2048 + ((k>>4)&1)*1024
//               + ((k>>5)&3)*256 + (r&15)*16 + (k&15)
// -> each 2KB k-block stages as two contiguous 1KB global_load_lds copies;
//    fragment = two ds_read_b128 at blk + lane*16 / +1024 (0 bank conflicts,
//    measured).
//
// Round-3 structure: 64x128 wave tiles (one strip), 8 K-steps of BK=128,
// double-buffered LDS, ONE barrier per K-step with the vmcnt wait covered by
// a full compute phase (T4), full unroll -> immediate ds offsets, setprio
// around the MFMA cluster (T5). Round-2's 2-phase lockstep measured 19%
// MfmaUtil = the known ~930TF 2-barrier structure ceiling; this breaks it.

#define HDIM 1024
#define NROW 8192
#define TEMP_INV (1.0f / 0.07f)

typedef __attribute__((ext_vector_type(4))) float float4v;  // MFMA C/D
typedef __attribute__((ext_vector_type(2))) float float2v;
typedef __attribute__((ext_vector_type(4))) int   int4v;
typedef __attribute__((ext_vector_type(8))) int   int8v;    // MFMA A/B (32B)

// ws layout (bytes)
#define SN_OFF   ((size_t)0)                        // 8 MB fp8 tiled S
#define TN_OFF   ((size_t)8388608)                  // 8 MB fp8 tiled T
#define TR_OFF   ((size_t)16777216)                 // 8 MB fp8 row-major T
#define SUM_OFF  ((size_t)25165824)                 // 8192 float sum-exp
#define PMX_OFF  (SUM_OFF + 32768)                  // 8192 u64 packed (max,~idx)
#define ACC_OFF  (PMX_OFF + 65536)                  // 2 floats
#define CNT_OFF  (ACC_OFF + 64)                     // 1 uint

// async 16B global -> LDS (per-lane gptr; lane i lands at lds_base + i*16)
static __device__ __forceinline__ void gload_lds16(const void* gptr, void* lptr) {
    __builtin_amdgcn_global_load_lds(
        (const __attribute__((address_space(1))) void*)gptr,
        (__attribute__((address_space(3))) void*)(uintptr_t)(uint32_t)(uintptr_t)lptr,
        16, 0, 0);
}

// dot of 4 fp8 pairs packed in two dwords
static __device__ __forceinline__ float fp8dot4(unsigned a, unsigned b) {
    float2v al = __builtin_amdgcn_cvt_pk_f32_fp8((int)a, false);
    float2v ah = __builtin_amdgcn_cvt_pk_f32_fp8((int)a, true);
    float2v bl = __builtin_amdgcn_cvt_pk_f32_fp8((int)b, false);
    float2v bh = __builtin_amdgcn_cvt_pk_f32_fp8((int)b, true);
    return al[0]*bl[0] + al[1]*bl[1] + ah[0]*bh[0] + ah[1]*bh[1];
}

// ---------------- Phase 0: normalize -> fp8, fully coalesced -------------------
__global__ __launch_bounds__(256)
void norm_kernel(const float* __restrict__ hs, const float* __restrict__ ht,
                 char* __restrict__ Sn, char* __restrict__ Tn, char* __restrict__ Tr,
                 float* __restrict__ sumexp, unsigned long long* __restrict__ pmax,
                 float* __restrict__ acc, unsigned* __restrict__ cnt) {
    const int b = blockIdx.x;                       // 0..1023
    const int t = threadIdx.x;
    const int wave = t >> 6, lane = t & 63;
    const bool isT = (b >= 512);
    const int g = isT ? (b - 512) : b;
    const float* in = (isT ? ht : hs) + (size_t)g * 16 * HDIM;
    char* outTiled = (isT ? Tn : Sn) + (size_t)g * 16384;

    __shared__ float sq[16][256];                   // 16 KB, reused as tiled buf
    __shared__ float sscale[16];

    float4v v[16];
    #pragma unroll
    for (int i = 0; i < 16; ++i) {
        v[i] = ((const float4v*)in)[i * 256 + t];
        sq[i][t] = v[i][0]*v[i][0] + v[i][1]*v[i][1] + v[i][2]*v[i][2] + v[i][3]*v[i][3];
    }
    __syncthreads();
    #pragma unroll
    for (int j = 0; j < 4; ++j) {
        const int ri = wave * 4 + j;
        float s = sq[ri][lane] + sq[ri][lane + 64] + sq[ri][lane + 128] + sq[ri][lane + 192];
        #pragma unroll
        for (int off = 1; off < 64; off <<= 1) s += __shfl_xor(s, off);
        if (lane == 0) sscale[ri] = 1.0f / fmaxf(sqrtf(s), 1e-12f);
    }
    __syncthreads();                                // scales ready; sq reads done

    // thread t owns k = 4t..4t+3 for all 16 rows.
    // off(r,4t) = (t>>5)*2048 + ((t>>2)&1)*1024 + ((t>>3)&3)*256 + r*16 + (t&3)*4
    char* tiled = (char*)sq;
    const int koff = (t >> 5) * 2048 + ((t >> 2) & 1) * 1024
                   + ((t >> 3) & 3) * 256 + (t & 3) * 4;
    #pragma unroll
    for (int i = 0; i < 16; ++i) {
        const float sc = sscale[i];
        int d = __builtin_amdgcn_cvt_pk_fp8_f32(v[i][0]*sc, v[i][1]*sc, 0, false);
        d     = __builtin_amdgcn_cvt_pk_fp8_f32(v[i][2]*sc, v[i][3]*sc, d, true);
        *(int*)(tiled + koff + i * 16) = d;
        if (isT) ((int*)(Tr + (size_t)(g * 16 + i) * HDIM))[t] = d;   // coalesced
    }
    __syncthreads();
    #pragma unroll
    for (int j = 0; j < 4; ++j)
        ((uint4*)outTiled)[j * 256 + t] = ((const uint4*)tiled)[j * 256 + t];

    if (!isT && t < 16) { sumexp[b * 16 + t] = 0.f; pmax[b * 16 + t] = 0ull; }
    if (b == 0 && t == 16) { acc[0] = 0.f; acc[1] = 0.f; *cnt = 0u; }
}

// ---------------- Phase 1: MX-fp8 K=128 pipelined flash pass -------------------
// Grid 1024 = 32 row-tiles x 32 col-tiles of 256x256. Block = 512 thr = 8 waves
// (4 row x 2 col), wave tile 64x128 (4x8 frags, acc in 128 AGPRs). 8 K-steps of
// BK=128, double-buffered LDS (A 2x32K + B 2x32K = 128 KB). Per step:
//   vmcnt(0) [loads issued a full compute phase ago] -> s_barrier ->
//   STAGE(kb+1) -> ds_read frags -> setprio(1) 32 MFMA setprio(0).
// One barrier per step; the stage wait is always covered. Fully unrolled so
// every ds_read offset is a compile-time immediate (no per-iter address VALU).
// amdgpu_waves_per_eu(2,2) pins the 256-VGPR budget (acc 128 AGPR + ~90 VGPR,
// no spill; round-1 failure mode was the allocator targeting 6 waves/EU).
__global__ __launch_bounds__(512)
__attribute__((amdgpu_waves_per_eu(2, 2)))
void flash_kernel(const char* __restrict__ Sn, const char* __restrict__ Tn,
                  float* __restrict__ sumexp, unsigned long long* __restrict__ pmax) {
    __shared__ __align__(16) char As[2][32768];     // 16 rowgroups x 2KB, x2 buf
    __shared__ __align__(16) char Bs[2][32768];     // 16 colgroups x 2KB, x2 buf
    __shared__ float pbSe[256];
    __shared__ unsigned long long pbPk[256];

    const int t = threadIdx.x;
    const int wave = t >> 6, lane = t & 63;
    const int quad = lane >> 4, l16 = lane & 15;
    const int rbase = (int)(blockIdx.x & 31) * 256;
    const int rb16  = rbase >> 4;
    const int cb16  = (int)(blockIdx.x >> 5) * 16;
    const int wr = wave & 3, wc = wave >> 2;
    const int wm = wr * 64;

    // staging: 32 A units + 32 B units of 1KB; unit u: group u>>1, half u&1.
    // Each wave stages 4 A units and 4 B units per K-step.
    int offA[4], offB[4];
    #pragma unroll
    for (int u = 0; u < 4; ++u) {
        int ua = wave * 4 + u;
        offA[u] = (rb16 + (ua >> 1)) * 16384 + (ua & 1) * 1024 + lane * 16;
        offB[u] = (cb16 + (ua >> 1)) * 16384 + (ua & 1) * 1024 + lane * 16;
    }

    auto STAGE = [&](int kb) {                      // kb compile-time (unrolled)
        const int ks = kb * 2048;
        const int nb = kb & 1;
        #pragma unroll
        for (int u = 0; u < 4; ++u)
            gload_lds16(Sn + offA[u] + ks, &As[nb][(wave * 4 + u) * 1024]);
        #pragma unroll
        for (int u = 0; u < 4; ++u)
            gload_lds16(Tn + offB[u] + ks, &Bs[nb][(wave * 4 + u) * 1024]);
    };

    float4v acc[4][8];
    #pragma unroll
    for (int i = 0; i < 4; ++i)
        #pragma unroll
        for (int j = 0; j < 8; ++j) acc[i][j] = (float4v){0.f, 0.f, 0.f, 0.f};
    const int usc = 0x7f7f7f7f;                     // e8m0 127 -> scale 1.0

    STAGE(0);

    #pragma unroll
    for (int kb = 0; kb < 8; ++kb) {
        // stage(kb) loads were issued one full compute phase ago (except kb=0):
        // this wait is covered. All waves wait their own loads, then barrier ->
        // buf kb fully landed, and buf kb^1 (overwritten by STAGE below) has
        // been fully consumed by every wave (program order before barrier).
        asm volatile("s_waitcnt vmcnt(0)" ::: "memory");
        __builtin_amdgcn_s_barrier();
        if (kb < 7) STAGE(kb + 1);

        const char* Ab = As[kb & 1];
        const char* Bb = Bs[kb & 1];
        int8v af[4];
        #pragma unroll
        for (int i = 0; i < 4; ++i) {
            int4v lo = *(const int4v*)(Ab + (wr * 4 + i) * 2048 + lane * 16);
            int4v hi = *(const int4v*)(Ab + (wr * 4 + i) * 2048 + 1024 + lane * 16);
            af[i] = __builtin_shufflevector(lo, hi, 0, 1, 2, 3, 4, 5, 6, 7);
        }
        __builtin_amdgcn_s_setprio(1);
        #pragma unroll
        for (int j = 0; j < 8; ++j) {
            int4v lo = *(const int4v*)(Bb + (wc * 8 + j) * 2048 + lane * 16);
            int4v hi = *(const int4v*)(Bb + (wc * 8 + j) * 2048 + 1024 + lane * 16);
            int8v bf = __builtin_shufflevector(lo, hi, 0, 1, 2, 3, 4, 5, 6, 7);
            #pragma unroll
            for (int i = 0; i < 4; ++i)
                acc[i][j] = __builtin_amdgcn_mfma_scale_f32_16x16x128_f8f6f4(
                    af[i], bf, acc[i][j], 0, 0, 0, usc, 0, usc);
        }
        __builtin_amdgcn_s_setprio(0);
    }

    // epilogue: lane holds sim[rbase+wm+i*16+quad*4+r][cbase+j*16+l16]
    const int cbase = (int)(blockIdx.x >> 5) * 256 + wc * 128;
    float se_v[4][4]; unsigned long long pk_v[4][4];
    #pragma unroll
    for (int i = 0; i < 4; ++i) {
        #pragma unroll
        for (int r = 0; r < 4; ++r) {
            float se = 0.f; float mx = -2.f; int mi = 0x7fffffff;
            #pragma unroll
            for (int j = 0; j < 8; ++j) {
                float v = acc[i][j][r];
                se += __expf(v * TEMP_INV);
                int col = cbase + j * 16 + l16;
                if (v > mx || (v == mx && col < mi)) { mx = v; mi = col; }
            }
            #pragma unroll
            for (int off = 1; off < 16; off <<= 1) {
                se += __shfl_xor(se, off);
                float om = __shfl_xor(mx, off);
                int oi = __shfl_xor(mi, off);
                if (om > mx || (om == mx && oi < mi)) { mx = om; mi = oi; }
            }
            se_v[i][r] = se;
            pk_v[i][r] = ((unsigned long long)__float_as_uint(mx + 2.0f) << 32)
                         | (unsigned long long)(0xffffffffu - (unsigned)mi);
        }
    }
    // combine col-halves: waves 0..3 (cols 0-127) publish; 4..7 combine+atomic
    if (wave < 4 && l16 == 0) {
        #pragma unroll
        for (int i = 0; i < 4; ++i)
            #pragma unroll
            for (int r = 0; r < 4; ++r) {
                int rl = wm + i * 16 + quad * 4 + r;
                pbSe[rl] = se_v[i][r]; pbPk[rl] = pk_v[i][r];
            }
    }
    __syncthreads();
    if (wave >= 4 && l16 == 0) {
        #pragma unroll
        for (int i = 0; i < 4; ++i)
            #pragma unroll
            for (int r = 0; r < 4; ++r) {
                int rl = wm + i * 16 + quad * 4 + r;
                float se = se_v[i][r] + pbSe[rl];
                unsigned long long pk = pk_v[i][r];
                unsigned long long po = pbPk[rl];
                if (po > pk) pk = po;
                atomicAdd(&sumexp[rbase + rl], se);
                atomicMax(&pmax[rbase + rl], pk);
            }
    }
}

// ---------------- Phase 2: fused loss + ctx + finalize -------------------------
__global__ __launch_bounds__(256)
void tail_kernel(const float* __restrict__ sumexp,
                 const unsigned long long* __restrict__ pmax,
                 const char* __restrict__ Tr,
                 float* __restrict__ acc, unsigned* __restrict__ cnt,
                 float* __restrict__ out) {
    const int blk = blockIdx.x;                     // 0..255
    const int t = threadIdx.x, wave = t >> 6, lane = t & 63;

    if (wave == 0) {
        int r = blk * 32 + (lane & 31);
        unsigned long long p = pmax[r];
        float mx = __uint_as_float((unsigned)(p >> 32)) - 2.0f;
        float loss = logf(sumexp[r]) - mx * TEMP_INV;
        #pragma unroll
        for (int off = 1; off < 32; off <<= 1) loss += __shfl_xor(loss, off);
        if (lane == 0) atomicAdd(acc + 0, loss);    // lanes 0..31 summed once
    }

    float s = 0.f;
    #pragma unroll
    for (int it = 0; it < 8; ++it) {
        int g = blk * 32 + wave * 8 + it;
        if (g < NROW - 1) {
            unsigned long long pa = pmax[g], pb = pmax[g + 1];
            int ia = (int)(0xffffffffu - (unsigned)(pa & 0xffffffffu));
            int ib = (int)(0xffffffffu - (unsigned)(pb & 0xffffffffu));
            uint4 va = ((const uint4*)(Tr + (size_t)ia * HDIM))[lane];
            uint4 vb = ((const uint4*)(Tr + (size_t)ib * HDIM))[lane];
            s += fp8dot4(va.x, vb.x) + fp8dot4(va.y, vb.y)
               + fp8dot4(va.z, vb.z) + fp8dot4(va.w, vb.w);
        }
    }
    #pragma unroll
    for (int off = 1; off < 64; off <<= 1) s += __shfl_xor(s, off);
    __shared__ float red[4];
    if (lane == 0) red[wave] = s;
    __syncthreads();
    if (t == 0) atomicAdd(acc + 1, red[0] + red[1] + red[2] + red[3]);

    __threadfence();
    __shared__ unsigned done;
    if (t == 0) done = atomicAdd(cnt, 1u);
    __syncthreads();
    if (t == 0 && done == 255u) {
        float l0 = atomicAdd(acc + 0, 0.0f);        // device-scope RMW read
        float l1 = atomicAdd(acc + 1, 0.0f);
        out[0] = l0 / (float)NROW;
        out[1] = 1.0f - l1 / (float)(NROW - 1);
    }
}

extern "C" void kernel_launch(void* const* d_in, const int* in_sizes, int n_in,
                              void* d_out, int out_size, void* d_ws, size_t ws_size,
                              hipStream_t stream) {
    const float* hs = (const float*)d_in[0];
    const float* ht = (const float*)d_in[1];
    char* ws = (char*)d_ws;
    char* Sn = ws + SN_OFF;
    char* Tn = ws + TN_OFF;
    char* Tr = ws + TR_OFF;
    float* sumexp = (float*)(ws + SUM_OFF);
    unsigned long long* pmax = (unsigned long long*)(ws + PMX_OFF);
    float* acc = (float*)(ws + ACC_OFF);
    unsigned* cnt = (unsigned*)(ws + CNT_OFF);
    float* out = (float*)d_out;

    norm_kernel<<<1024, 256, 0, stream>>>(hs, ht, Sn, Tn, Tr, sumexp, pmax, acc, cnt);
    flash_kernel<<<1024, 512, 0, stream>>>(Sn, Tn, sumexp, pmax);
    tail_kernel<<<256, 256, 0, stream>>>(sumexp, pmax, Tr, acc, cnt, out);
}

// Round 6
// 238.437 us; speedup vs baseline: 5.1050x; 5.1050x over previous
//
#include <hip/hip_runtime.h>
#include <hip/hip_bf16.h>
#include <stdint.h>

// B=16,T=512,H=1024 -> N=M=8192 rows, H=1024.
// out[0] = mean_i [ log(sum_j exp(sim_ij/T)) - max_j sim_ij / T ]
// out[1] = 1 - mean_i dot(Tn[pos[i]], Tn[pos[i+1]])
// sim computed in fp8 e4m3 via MX-scaled MFMA 16x16x128_f8f6f4 with unity
// scales (e8m0 0x7f = 2^0) -> numerically identical to plain fp8, 2.27x rate.
//
// fp8 tiled layout (per 16-row group of 16KB), K=128 fragment
// (lane l: row l&15, k=(l>>4)*32 + 0..31):
//   row r, k -> group g=r>>4, off = (k>>7)*2048 + ((k>>4)&1)*1024
//               + ((k>>5)&3)*256 + (r&15)*16 + (k&15)
// -> each 2KB k-block stages as two contiguous 1KB global_load_lds copies;
//    fragment = two ds_read_b128 at blk + lane*16 / +1024 (0 bank conflicts,
//    measured).
//
// Round-6: round-4/5 schedule with the barrier race-proofed. Rounds 4/5
// failed to run; their only novel construct vs HW-proven code was
// builtin s_barrier WITHOUT a compiler memory fence -> hipcc may sink next
// iteration's ds_reads above the barrier (race with other waves' staging).
// Reverted to round-2's proven combined asm: "s_waitcnt vmcnt(0); s_barrier"
// in ONE asm volatile with "memory" clobber. Loop kept #pragma unroll 1
// (round-3 lesson: full unroll -> cross-iteration pipelining on top of the
// 128-AGPR accumulator -> 256-reg budget blown -> 3.5 GB scratch).

#define HDIM 1024
#define NROW 8192
#define TEMP_INV (1.0f / 0.07f)

typedef __attribute__((ext_vector_type(4))) float float4v;  // MFMA C/D
typedef __attribute__((ext_vector_type(2))) float float2v;
typedef __attribute__((ext_vector_type(4))) int   int4v;
typedef __attribute__((ext_vector_type(8))) int   int8v;    // MFMA A/B (32B)

// ws layout (bytes)
#define SN_OFF   ((size_t)0)                        // 8 MB fp8 tiled S
#define TN_OFF   ((size_t)8388608)                  // 8 MB fp8 tiled T
#define TR_OFF   ((size_t)16777216)                 // 8 MB fp8 row-major T
#define SUM_OFF  ((size_t)25165824)                 // 8192 float sum-exp
#define PMX_OFF  (SUM_OFF + 32768)                  // 8192 u64 packed (max,~idx)
#define ACC_OFF  (PMX_OFF + 65536)                  // 2 floats
#define CNT_OFF  (ACC_OFF + 64)                     // 1 uint

// async 16B global -> LDS (per-lane gptr; lane i lands at lds_base + i*16)
static __device__ __forceinline__ void gload_lds16(const void* gptr, void* lptr) {
    __builtin_amdgcn_global_load_lds(
        (const __attribute__((address_space(1))) void*)gptr,
        (__attribute__((address_space(3))) void*)(uintptr_t)(uint32_t)(uintptr_t)lptr,
        16, 0, 0);
}

// dot of 4 fp8 pairs packed in two dwords
static __device__ __forceinline__ float fp8dot4(unsigned a, unsigned b) {
    float2v al = __builtin_amdgcn_cvt_pk_f32_fp8((int)a, false);
    float2v ah = __builtin_amdgcn_cvt_pk_f32_fp8((int)a, true);
    float2v bl = __builtin_amdgcn_cvt_pk_f32_fp8((int)b, false);
    float2v bh = __builtin_amdgcn_cvt_pk_f32_fp8((int)b, true);
    return al[0]*bl[0] + al[1]*bl[1] + ah[0]*bh[0] + ah[1]*bh[1];
}

// ---------------- Phase 0: normalize -> fp8, fully coalesced -------------------
__global__ __launch_bounds__(256)
void norm_kernel(const float* __restrict__ hs, const float* __restrict__ ht,
                 char* __restrict__ Sn, char* __restrict__ Tn, char* __restrict__ Tr,
                 float* __restrict__ sumexp, unsigned long long* __restrict__ pmax,
                 float* __restrict__ acc, unsigned* __restrict__ cnt) {
    const int b = blockIdx.x;                       // 0..1023
    const int t = threadIdx.x;
    const int wave = t >> 6, lane = t & 63;
    const bool isT = (b >= 512);
    const int g = isT ? (b - 512) : b;
    const float* in = (isT ? ht : hs) + (size_t)g * 16 * HDIM;
    char* outTiled = (isT ? Tn : Sn) + (size_t)g * 16384;

    __shared__ float sq[16][256];                   // 16 KB, reused as tiled buf
    __shared__ float sscale[16];

    float4v v[16];
    #pragma unroll
    for (int i = 0; i < 16; ++i) {
        v[i] = ((const float4v*)in)[i * 256 + t];
        sq[i][t] = v[i][0]*v[i][0] + v[i][1]*v[i][1] + v[i][2]*v[i][2] + v[i][3]*v[i][3];
    }
    __syncthreads();
    #pragma unroll
    for (int j = 0; j < 4; ++j) {
        const int ri = wave * 4 + j;
        float s = sq[ri][lane] + sq[ri][lane + 64] + sq[ri][lane + 128] + sq[ri][lane + 192];
        #pragma unroll
        for (int off = 1; off < 64; off <<= 1) s += __shfl_xor(s, off);
        if (lane == 0) sscale[ri] = 1.0f / fmaxf(sqrtf(s), 1e-12f);
    }
    __syncthreads();                                // scales ready; sq reads done

    // thread t owns k = 4t..4t+3 for all 16 rows.
    // off(r,4t) = (t>>5)*2048 + ((t>>2)&1)*1024 + ((t>>3)&3)*256 + r*16 + (t&3)*4
    char* tiled = (char*)sq;
    const int koff = (t >> 5) * 2048 + ((t >> 2) & 1) * 1024
                   + ((t >> 3) & 3) * 256 + (t & 3) * 4;
    #pragma unroll
    for (int i = 0; i < 16; ++i) {
        const float sc = sscale[i];
        int d = __builtin_amdgcn_cvt_pk_fp8_f32(v[i][0]*sc, v[i][1]*sc, 0, false);
        d     = __builtin_amdgcn_cvt_pk_fp8_f32(v[i][2]*sc, v[i][3]*sc, d, true);
        *(int*)(tiled + koff + i * 16) = d;
        if (isT) ((int*)(Tr + (size_t)(g * 16 + i) * HDIM))[t] = d;   // coalesced
    }
    __syncthreads();
    #pragma unroll
    for (int j = 0; j < 4; ++j)
        ((uint4*)outTiled)[j * 256 + t] = ((const uint4*)tiled)[j * 256 + t];

    if (!isT && t < 16) { sumexp[b * 16 + t] = 0.f; pmax[b * 16 + t] = 0ull; }
    if (b == 0 && t == 16) { acc[0] = 0.f; acc[1] = 0.f; *cnt = 0u; }
}

// ---------------- Phase 1: MX-fp8 K=128 pipelined flash pass -------------------
// Grid 1024 = 32 row-tiles x 32 col-tiles of 256x256. Block = 512 thr = 8 waves
// (4 row x 2 col), wave tile 64x128 (4x8 frags, acc in 128 AGPRs). 8 K-steps of
// BK=128, double-buffered LDS (A 2x32K + B 2x32K = 128 KB). Per step:
//   STAGE(kb+1) -> ds_read frags -> setprio(1) 32 MFMA setprio(0) ->
//   {vmcnt(0); s_barrier} as ONE fenced asm (wait covered by compute phase).
// amdgpu_waves_per_eu(2,2) pins the 256-VGPR budget (round-1 lesson).
__global__ __launch_bounds__(512)
__attribute__((amdgpu_waves_per_eu(2, 2)))
void flash_kernel(const char* __restrict__ Sn, const char* __restrict__ Tn,
                  float* __restrict__ sumexp, unsigned long long* __restrict__ pmax) {
    __shared__ __align__(16) char As[2][32768];     // 16 rowgroups x 2KB, x2 buf
    __shared__ __align__(16) char Bs[2][32768];     // 16 colgroups x 2KB, x2 buf
    __shared__ float pbSe[256];
    __shared__ unsigned long long pbPk[256];

    const int t = threadIdx.x;
    const int wave = t >> 6, lane = t & 63;
    const int quad = lane >> 4, l16 = lane & 15;
    const int rbase = (int)(blockIdx.x & 31) * 256;
    const int rb16  = rbase >> 4;
    const int cb16  = (int)(blockIdx.x >> 5) * 16;
    const int wr = wave & 3, wc = wave >> 2;
    const int wm = wr * 64;

    // staging: 32 A units + 32 B units of 1KB; unit u: group u>>1, half u&1.
    int offA[4], offB[4];
    #pragma unroll
    for (int u = 0; u < 4; ++u) {
        int ua = wave * 4 + u;
        offA[u] = (rb16 + (ua >> 1)) * 16384 + (ua & 1) * 1024 + lane * 16;
        offB[u] = (cb16 + (ua >> 1)) * 16384 + (ua & 1) * 1024 + lane * 16;
    }

    auto STAGE = [&](int kb) {
        const int ks = kb * 2048;
        const int nb = kb & 1;
        #pragma unroll
        for (int u = 0; u < 4; ++u)
            gload_lds16(Sn + offA[u] + ks, &As[nb][(wave * 4 + u) * 1024]);
        #pragma unroll
        for (int u = 0; u < 4; ++u)
            gload_lds16(Tn + offB[u] + ks, &Bs[nb][(wave * 4 + u) * 1024]);
    };

    float4v acc[4][8];
    #pragma unroll
    for (int i = 0; i < 4; ++i)
        #pragma unroll
        for (int j = 0; j < 8; ++j) acc[i][j] = (float4v){0.f, 0.f, 0.f, 0.f};
    const int usc = 0x7f7f7f7f;                     // e8m0 127 -> scale 1.0

    STAGE(0);
    asm volatile("s_waitcnt vmcnt(0)\ns_barrier" ::: "memory");

    #pragma unroll 1
    for (int kb = 0; kb < 8; ++kb) {
        if (kb < 7) STAGE(kb + 1);                  // issue-early into buf^1

        const char* Ab = As[kb & 1];
        const char* Bb = Bs[kb & 1];
        int8v af[4];
        #pragma unroll
        for (int i = 0; i < 4; ++i) {
            int4v lo = *(const int4v*)(Ab + (wr * 4 + i) * 2048 + lane * 16);
            int4v hi = *(const int4v*)(Ab + (wr * 4 + i) * 2048 + 1024 + lane * 16);
            af[i] = __builtin_shufflevector(lo, hi, 0, 1, 2, 3, 4, 5, 6, 7);
        }
        __builtin_amdgcn_s_setprio(1);
        #pragma unroll
        for (int j = 0; j < 8; ++j) {
            int4v lo = *(const int4v*)(Bb + (wc * 8 + j) * 2048 + lane * 16);
            int4v hi = *(const int4v*)(Bb + (wc * 8 + j) * 2048 + 1024 + lane * 16);
            int8v bf = __builtin_shufflevector(lo, hi, 0, 1, 2, 3, 4, 5, 6, 7);
            #pragma unroll
            for (int i = 0; i < 4; ++i)
                acc[i][j] = __builtin_amdgcn_mfma_scale_f32_16x16x128_f8f6f4(
                    af[i], bf, acc[i][j], 0, 0, 0, usc, 0, usc);
        }
        __builtin_amdgcn_s_setprio(0);

        // STAGE(kb+1) was issued a full compute phase ago -> wait is covered.
        // Single fenced asm: compiler cannot move next iteration's ds_reads
        // above this barrier (the round-4/5 builtin-barrier form lacked the
        // fence). After it: buf kb+1 landed for ALL waves; buf kb consumed by
        // all waves -> next STAGE may overwrite buf kb^1's partner safely.
        asm volatile("s_waitcnt vmcnt(0)\ns_barrier" ::: "memory");
    }

    // epilogue: lane holds sim[rbase+wm+i*16+quad*4+r][cbase+j*16+l16]
    const int cbase = (int)(blockIdx.x >> 5) * 256 + wc * 128;
    float se_v[4][4]; unsigned long long pk_v[4][4];
    #pragma unroll
    for (int i = 0; i < 4; ++i) {
        #pragma unroll
        for (int r = 0; r < 4; ++r) {
            float se = 0.f; float mx = -2.f; int mi = 0x7fffffff;
            #pragma unroll
            for (int j = 0; j < 8; ++j) {
                float v = acc[i][j][r];
                se += __expf(v * TEMP_INV);
                int col = cbase + j * 16 + l16;
                if (v > mx || (v == mx && col < mi)) { mx = v; mi = col; }
            }
            #pragma unroll
            for (int off = 1; off < 16; off <<= 1) {
                se += __shfl_xor(se, off);
                float om = __shfl_xor(mx, off);
                int oi = __shfl_xor(mi, off);
                if (om > mx || (om == mx && oi < mi)) { mx = om; mi = oi; }
            }
            se_v[i][r] = se;
            pk_v[i][r] = ((unsigned long long)__float_as_uint(mx + 2.0f) << 32)
                         | (unsigned long long)(0xffffffffu - (unsigned)mi);
        }
    }
    // combine col-halves: waves 0..3 (cols 0-127) publish; 4..7 combine+atomic
    if (wave < 4 && l16 == 0) {
        #pragma unroll
        for (int i = 0; i < 4; ++i)
            #pragma unroll
            for (int r = 0; r < 4; ++r) {
                int rl = wm + i * 16 + quad * 4 + r;
                pbSe[rl] = se_v[i][r]; pbPk[rl] = pk_v[i][r];
            }
    }
    __syncthreads();
    if (wave >= 4 && l16 == 0) {
        #pragma unroll
        for (int i = 0; i < 4; ++i)
            #pragma unroll
            for (int r = 0; r < 4; ++r) {
                int rl = wm + i * 16 + quad * 4 + r;
                float se = se_v[i][r] + pbSe[rl];
                unsigned long long pk = pk_v[i][r];
                unsigned long long po = pbPk[rl];
                if (po > pk) pk = po;
                atomicAdd(&sumexp[rbase + rl], se);
                atomicMax(&pmax[rbase + rl], pk);
            }
    }
}

// ---------------- Phase 2: fused loss + ctx + finalize -------------------------
__global__ __launch_bounds__(256)
void tail_kernel(const float* __restrict__ sumexp,
                 const unsigned long long* __restrict__ pmax,
                 const char* __restrict__ Tr,
                 float* __restrict__ acc, unsigned* __restrict__ cnt,
                 float* __restrict__ out) {
    const int blk = blockIdx.x;                     // 0..255
    const int t = threadIdx.x, wave = t >> 6, lane = t & 63;

    if (wave == 0) {
        int r = blk * 32 + (lane & 31);
        unsigned long long p = pmax[r];
        float mx = __uint_as_float((unsigned)(p >> 32)) - 2.0f;
        float loss = logf(sumexp[r]) - mx * TEMP_INV;
        #pragma unroll
        for (int off = 1; off < 32; off <<= 1) loss += __shfl_xor(loss, off);
        if (lane == 0) atomicAdd(acc + 0, loss);    // lanes 0..31 summed once
    }

    float s = 0.f;
    #pragma unroll
    for (int it = 0; it < 8; ++it) {
        int g = blk * 32 + wave * 8 + it;
        if (g < NROW - 1) {
            unsigned long long pa = pmax[g], pb = pmax[g + 1];
            int ia = (int)(0xffffffffu - (unsigned)(pa & 0xffffffffu));
            int ib = (int)(0xffffffffu - (unsigned)(pb & 0xffffffffu));
            uint4 va = ((const uint4*)(Tr + (size_t)ia * HDIM))[lane];
            uint4 vb = ((const uint4*)(Tr + (size_t)ib * HDIM))[lane];
            s += fp8dot4(va.x, vb.x) + fp8dot4(va.y, vb.y)
               + fp8dot4(va.z, vb.z) + fp8dot4(va.w, vb.w);
        }
    }
    #pragma unroll
    for (int off = 1; off < 64; off <<= 1) s += __shfl_xor(s, off);
    __shared__ float red[4];
    if (lane == 0) red[wave] = s;
    __syncthreads();
    if (t == 0) atomicAdd(acc + 1, red[0] + red[1] + red[2] + red[3]);

    __threadfence();
    __shared__ unsigned done;
    if (t == 0) done = atomicAdd(cnt, 1u);
    __syncthreads();
    if (t == 0 && done == 255u) {
        float l0 = atomicAdd(acc + 0, 0.0f);        // device-scope RMW read
        float l1 = atomicAdd(acc + 1, 0.0f);
        out[0] = l0 / (float)NROW;
        out[1] = 1.0f - l1 / (float)(NROW - 1);
    }
}

extern "C" void kernel_launch(void* const* d_in, const int* in_sizes, int n_in,
                              void* d_out, int out_size, void* d_ws, size_t ws_size,
                              hipStream_t stream) {
    const float* hs = (const float*)d_in[0];
    const float* ht = (const float*)d_in[1];
    char* ws = (char*)d_ws;
    char* Sn = ws + SN_OFF;
    char* Tn = ws + TN_OFF;
    char* Tr = ws + TR_OFF;
    float* sumexp = (float*)(ws + SUM_OFF);
    unsigned long long* pmax = (unsigned long long*)(ws + PMX_OFF);
    float* acc = (float*)(ws + ACC_OFF);
    unsigned* cnt = (unsigned*)(ws + CNT_OFF);
    float* out = (float*)d_out;

    norm_kernel<<<1024, 256, 0, stream>>>(hs, ht, Sn, Tn, Tr, sumexp, pmax, acc, cnt);
    flash_kernel<<<1024, 512, 0, stream>>>(Sn, Tn, sumexp, pmax);
    tail_kernel<<<256, 256, 0, stream>>>(sumexp, pmax, Tr, acc, cnt, out);
}